// Round 5
// baseline (403.688 us; speedup 1.0000x reference)
//
#include <hip/hip_runtime.h>
#include <cstddef>
#include <cstdint>

// ST-GCN block. Round-4 (resubmit): async global->LDS DMA pipeline (T3/T4 pattern).
//  - x staged as F32 directly to LDS via __builtin_amdgcn_global_load_lds
//    (zero register residency: rounds 2/3 proved reg-held prefetch gets
//    spilled/sunk -> +100MB scratch traffic). Double-buffered Xf[2][64][50].
//  - NO __syncthreads (it drains vmcnt(0)). Raw s_barrier + manual waits:
//      B0: s_waitcnt vmcnt(N) lgkmcnt(0)  -- N counted so the NEXT tile's DMA
//          and prior stores stay in flight across the whole iteration.
//      B1: s_waitcnt lgkmcnt(0) only (Ys write->read ordering).
//    Outstanding-op ledger per wave (L = DMA instrs/tile = 13 (wv<2) or 12):
//      tt=0: [D0,D1]              -> wait L   (drain D0)
//      tt=1: [D1,D2,S0]           -> wait L+8
//      tt=2..4: [Dt,S(t-2),D(t+1),S(t-1)] -> wait L+16
//      tt=5: [D5,S3,S4]           -> wait 16
//    DMA(tt+2) issued right after B1 (Xf[tt&1] has no readers after B1).
//    Pre-loop operand loads still outstanding at the first wait only make it
//    more conservative (drain-oldest), never under-wait.
//  - bf16 A-frags built at read time from f32 LDS (8x ds_read_b32 stride 200B,
//    ~4-way conflict = 1.58x, acceptable) with v_perm-based RNE pack
//    (bit-identical to round-0 numerics). Pad rows v>=25 masked to 0 in-reg.
//  - Residual read as f32 float2 from Xf (closer to ref than old bf16 path).
//  - Round-2-verified epilogue: wave owns (o-half,w-half), both m, dense
//    float2 stores.
// Sync proof: [B0,B1): Xf[cur] read-only, Ys write-only, DMA lands in Xf[cur^1].
//             [B1,B0'): Ys read-only, DMA(tt+2) lands in Xf[cur] (no readers).
#define N_  32
#define C_  64
#define T_  300
#define V_  25
#define M_  2
#define S_  3
#define O_  64
#define OS_ 192
#define TB  6             // t-values per block
#define NT_BLK (T_/TB)    // 50
#define CTVM (C_*T_*V_*M_)   // 960000
#define TVM  (T_*V_*M_)      // 15000
#define VM   (V_*M_)         // 50
#define XTILE (C_*VM)     // 3200 floats = 12.8 KB per t-tile
#define YPITCH 72

typedef short  short8  __attribute__((ext_vector_type(8)));
typedef float  float4_ __attribute__((ext_vector_type(4)));

__device__ __forceinline__ short f2bf(float f) {   // fp32 -> bf16 RNE (prep only)
    uint32_t u = __float_as_uint(f);
    u += 0x7FFFu + ((u >> 16) & 1u);
    return (short)(u >> 16);
}
// packed RNE: lo=bf16(a), hi=bf16(b); v_perm grabs the two high halves.
__device__ __forceinline__ unsigned pk2bf(float a, float b) {
    unsigned ua = __float_as_uint(a), ub = __float_as_uint(b);
    ua += 0x7FFFu + ((ua >> 16) & 1u);
    ub += 0x7FFFu + ((ub >> 16) & 1u);
    return __builtin_amdgcn_perm(ub, ua, 0x07060302u);
}

#define WAITV_LG(N) asm volatile("s_waitcnt vmcnt(" #N ") lgkmcnt(0)" ::: "memory")
#define WAIT_LG()   asm volatile("s_waitcnt lgkmcnt(0)" ::: "memory")
#define BARRIER()   do { __builtin_amdgcn_s_barrier(); asm volatile("" ::: "memory"); } while (0)

// issue one t-tile DMA: global x[c][vm] (rows 200B, stride 60000B) -> LDS linear.
// 50 instrs of 256B, strided across 4 waves (13/13/12/12). LDS dest wave-uniform;
// global addr per-lane. Increments vmcnt by L per wave.
__device__ __forceinline__ void dma_tile(const float* __restrict__ xt, float* dst,
                                         int wv, int lane)
{
    #pragma unroll
    for (int i = 0; i < 13; ++i) {
        const int q = wv + 4 * i;
        if (q < 50) {                       // wave-uniform
            const unsigned f = (unsigned)(q * 64 + lane);
            const unsigned c = f / 50u;
            const unsigned r = f - c * 50u;
            const float* g = xt + (size_t)c * TVM + r;
            __builtin_amdgcn_global_load_lds(
                (const __attribute__((address_space(1))) void*)g,
                (__attribute__((address_space(3))) void*)(dst + q * 64),
                4, 0, 0);
        }
    }
}

// prep: W -> bf16 [os][c]; PA -> bf16 transposed+padded [s][w32][v32]; BN fold.
__global__ void stgcn_prep(const float* __restrict__ Wc, const float* __restrict__ PA,
                           const float* __restrict__ g,  const float* __restrict__ b,
                           const float* __restrict__ mn, const float* __restrict__ vr,
                           short* __restrict__ Wb, short* __restrict__ PAb,
                           float* __restrict__ scl, float* __restrict__ sft)
{
    const int i = blockIdx.x * 256 + threadIdx.x;
    if (i < OS_ * C_) Wb[i] = f2bf(Wc[i]);
    const int r = i - OS_ * C_;
    if (r >= 0 && r < S_ * 32 * 32) {
        const int s = r >> 10, rem = r & 1023, wp = rem >> 5, vp = rem & 31;
        const float val = (wp < V_ && vp < V_) ? PA[s * V_ * V_ + vp * V_ + wp] : 0.0f;
        PAb[r] = f2bf(val);
    }
    const int q = r - S_ * 32 * 32;
    if (q >= 0 && q < O_) {
        const float sc = g[q] * rsqrtf(vr[q] + 1e-5f);
        scl[q] = sc;
        sft[q] = b[q] - mn[q] * sc;
    }
}

__global__ __launch_bounds__(256, 3)
void stgcn_main(const float* __restrict__ x, const float* __restrict__ cb,
                const short* __restrict__ Wb, const short* __restrict__ PAb,
                const float* __restrict__ sclg, const float* __restrict__ sftg,
                float* __restrict__ out)
{
    __shared__ float Xf[2 * XTILE];        // 25.6 KB f32, double-buffered
    __shared__ short Ys[OS_ * YPITCH];     // 27.6 KB
    __shared__ float sclS[O_], sftS[O_];   // total 53,760 B -> 3 blocks/CU

    const int tid  = threadIdx.x;
    const int wv   = tid >> 6;
    const int lane = tid & 63;
    const int quad = lane >> 4;
    const int l15  = lane & 15;

    const int n  = blockIdx.x / NT_BLK;
    const int t0 = (blockIdx.x % NT_BLK) * TB;
    const size_t xbase = (size_t)n * CTVM;

    if (tid < O_) { sclS[tid] = sclg[tid]; sftS[tid] = sftg[tid]; }

    // ---- wave-constant fragments ----
    const int wbase = wv * 48;            // stage-1: this wave's 48 os rows
    short8 aW[3][2];                      // B-operand: B[k=c][n=os]
    #pragma unroll
    for (int mt = 0; mt < 3; ++mt)
        #pragma unroll
        for (int ks = 0; ks < 2; ++ks)
            aW[mt][ks] = *(const short8*)(Wb + (wbase + mt * 16 + l15) * C_ + ks * 32 + quad * 8);

    float cbw[3];                         // stage-1 bias: per COLUMN (os = l15-mapped)
    #pragma unroll
    for (int mt = 0; mt < 3; ++mt) cbw[mt] = cb[wbase + mt * 16 + l15];

    // stage-2: wave owns (o-half, w-half); computes BOTH m
    const int oh = wv >> 1, hh = wv & 1;
    const int wc = hh * 16 + l15;
    short8 bP[3];                         // B[k=v][n=w]
    #pragma unroll
    for (int s = 0; s < 3; ++s)
        bP[s] = *(const short8*)(PAb + s * 1024 + wc * 32 + quad * 8);

    // ---- prologue: 2-deep DMA prefetch ----
    dma_tile(x + xbase + (size_t)t0 * VM,       Xf,         wv, lane);
    dma_tile(x + xbase + (size_t)(t0 + 1) * VM, Xf + XTILE, wv, lane);

    for (int tt = 0; tt < TB; ++tt) {
        // ---- B0: drain DMA(tt) only; leave DMA(tt+1)+stores in flight ----
        if (wv < 2) {
            if      (tt == 0) WAITV_LG(13);
            else if (tt == 1) WAITV_LG(21);
            else if (tt <  5) WAITV_LG(29);
            else              WAITV_LG(16);
        } else {
            if      (tt == 0) WAITV_LG(12);
            else if (tt == 1) WAITV_LG(20);
            else if (tt <  5) WAITV_LG(28);
            else              WAITV_LG(16);
        }
        BARRIER();

        const float* Xc = Xf + (tt & 1) * XTILE;

        // ---- build A-frags from f32 LDS (bit-identical RNE to round 0) ----
        short8 bX[4][2];                  // A[m=pos][k=c]
        #pragma unroll
        for (int nt = 0; nt < 4; ++nt) {
            const int pos = nt * 16 + l15;
            const int vm  = (pos & 31) * 2 + (pos >> 5);
            const unsigned keep = ((pos & 31) < V_) ? 0xFFFFFFFFu : 0u;  // zero pad rows
            #pragma unroll
            for (int ks = 0; ks < 2; ++ks) {
                const float* pb = Xc + (ks * 32 + quad * 8) * VM + vm;
                union { short8 s; unsigned u[4]; } U;
                #pragma unroll
                for (int j2 = 0; j2 < 4; ++j2)
                    U.u[j2] = pk2bf(pb[(2 * j2) * VM], pb[(2 * j2 + 1) * VM]) & keep;
                bX[nt][ks] = U.s;
            }
        }

        // ---- residual (f32), read before B1 ----
        float2 resv[2][4];                // [otl][r] = {m0, m1}
        #pragma unroll
        for (int otl = 0; otl < 2; ++otl)
            #pragma unroll
            for (int r = 0; r < 4; ++r) {
                const int o = (oh * 2 + otl) * 16 + quad * 4 + r;
                resv[otl][r] = *(const float2*)(Xc + o * VM + wc * 2);
            }

        // ---- stage 1: D[pos][os] = X^T·W^T + cb ----
        #pragma unroll
        for (int mt = 0; mt < 3; ++mt) {
            #pragma unroll
            for (int nt = 0; nt < 4; ++nt) {
                float4_ acc = { cbw[mt], cbw[mt], cbw[mt], cbw[mt] };
                acc = __builtin_amdgcn_mfma_f32_16x16x32_bf16(bX[nt][0], aW[mt][0], acc, 0, 0, 0);
                acc = __builtin_amdgcn_mfma_f32_16x16x32_bf16(bX[nt][1], aW[mt][1], acc, 0, 0, 0);
                const int os = wbase + mt * 16 + l15;
                *(uint2*)(Ys + os * YPITCH + nt * 16 + quad * 4) =
                    make_uint2(pk2bf(acc[0], acc[1]), pk2bf(acc[2], acc[3]));
            }
        }

        // ---- B1: Ys write->read ordering only; DMA stays in flight ----
        WAIT_LG();
        BARRIER();

        // ---- issue DMA(tt+2) into Xf[tt&1] (free: no readers after B1) ----
        if (tt + 2 < TB)
            dma_tile(x + xbase + (size_t)(t0 + tt + 2) * VM, Xf + (tt & 1) * XTILE, wv, lane);

        // ---- stage 2: Z[o][w] = sum_s Y_s[o][v] PA_s[v][w], both m per wave ----
        float4_ z[2][2];
        #pragma unroll
        for (int otl = 0; otl < 2; ++otl)
            #pragma unroll
            for (int m = 0; m < 2; ++m) { z[otl][m][0]=0.f; z[otl][m][1]=0.f; z[otl][m][2]=0.f; z[otl][m][3]=0.f; }
        #pragma unroll
        for (int s = 0; s < 3; ++s) {
            #pragma unroll
            for (int otl = 0; otl < 2; ++otl) {
                #pragma unroll
                for (int m = 0; m < 2; ++m) {
                    const short8 aY = *(const short8*)(Ys + (s * 64 + (oh * 2 + otl) * 16 + l15) * YPITCH + m * 32 + quad * 8);
                    z[otl][m] = __builtin_amdgcn_mfma_f32_16x16x32_bf16(aY, bP[s], z[otl][m], 0, 0, 0);
                }
            }
        }

        // ---- epilogue: BN + relu + residual(f32) + relu; dense float2 stores ----
        const int t = t0 + tt;
        if (wc < V_) {
            #pragma unroll
            for (int otl = 0; otl < 2; ++otl) {
                #pragma unroll
                for (int r = 0; r < 4; ++r) {
                    const int o = (oh * 2 + otl) * 16 + quad * 4 + r;
                    const float sc = sclS[o], sh = sftS[o];
                    float q0 = fmaf(z[otl][0][r], sc, sh);
                    q0 = fmaxf(q0, 0.0f);
                    q0 = fmaxf(q0 + resv[otl][r].x, 0.0f);
                    float q1 = fmaf(z[otl][1][r], sc, sh);
                    q1 = fmaxf(q1, 0.0f);
                    q1 = fmaxf(q1 + resv[otl][r].y, 0.0f);
                    *(float2*)(out + xbase + (size_t)o * TVM + (size_t)t * VM + wc * 2) =
                        make_float2(q0, q1);
                }
            }
        }
    }
}

extern "C" void kernel_launch(void* const* d_in, const int* in_sizes, int n_in,
                              void* d_out, int out_size, void* d_ws, size_t ws_size,
                              hipStream_t stream)
{
    const float* x    = (const float*)d_in[0];  // (32,64,300,25,2)
    const float* PA   = (const float*)d_in[1];  // (3,25,25)
    const float* Wc   = (const float*)d_in[2];  // (192,64)
    const float* cb   = (const float*)d_in[3];  // (192,)
    const float* bn_g = (const float*)d_in[4];
    const float* bn_b = (const float*)d_in[5];
    const float* bn_m = (const float*)d_in[6];
    const float* bn_v = (const float*)d_in[7];
    float* out = (float*)d_out;

    char* ws = (char*)d_ws;
    short* Wb  = (short*)ws;                    // 12288 bf16
    short* PAb = (short*)(ws + 24576);          //  3072 bf16
    float* scl = (float*)(ws + 30720);          //    64 f32
    float* sft = (float*)(ws + 30976);          //    64 f32

    stgcn_prep<<<61, 256, 0, stream>>>(Wc, PA, bn_g, bn_b, bn_m, bn_v, Wb, PAb, scl, sft);
    stgcn_main<<<N_ * NT_BLK, 256, 0, stream>>>(x, cb, Wb, PAb, scl, sft, out);
}

// Round 6
// 277.938 us; speedup vs baseline: 1.4524x; 1.4524x over previous
//
#include <hip/hip_runtime.h>
#include <cstddef>
#include <cstdint>

// ST-GCN block. Round-6: single-barrier iteration, wave-private stage-1->stage-2
// handoff (no cross-wave Ys round-trip).
//  - Stage-1 re-mapped: wave wv owns o-block [wv*16, wv*16+16); computes the 3
//    subset tiles os = s*64 + wv*16 (+bias). D: lane l15 = o_local, rows pos =
//    nt*16 + quad*4 + r (pos = m*32 + v).
//  - Handoff: per (s,nt) pack acc -> uint2 (bf16 pairs), ds_write to PER-WAVE
//    scratch scr[wv][s][nt][lane] (stride-8B writes, conflict-free). Stage-2
//    A-frag (lane l15 = o, k = v = quad*8+j) assembled from two b64 reads:
//      u2[h] = scr[wv][s][2m+(quad>>1)][ (quad&1)*32 + 16h + l15 ]
//    (quad-pair broadcast reads, conflict-free). Same-wave RAW via lgkmcnt only
//    -> NO second barrier. One __syncthreads per iteration (Xb prod/cons).
//  - Stage-2: z[m][wh] (wh = w-half) = sum_s mfma(aY[s][m], bP[s][wh]); lane
//    holds both m for (o = wv*16+quad*4+r, w = wh*16+l15) -> dense float2 stores.
//  - Staging/prefetch: R0-proven code verbatim (float2 regs issued post-B0,
//    converted end-of-same-iteration, Xb double-buffered, (256,3)).
//    (R2/R3/R5 lessons: reg-prefetch beyond 16 VGPRs gets spilled; occupancy
//    isn't the lever; global_load_lds kills x's L3 residency. Don't touch.)
// Sync proof: [B0_t, B0_{t+1}): Xb[cur] read-only, Xb[cur^1] write-only,
//   scr[wv] accessed only by wave wv (program-ordered via lgkmcnt).
#define N_  32
#define C_  64
#define T_  300
#define V_  25
#define M_  2
#define S_  3
#define O_  64
#define OS_ 192
#define TB  6             // t-values per block
#define NT_BLK (T_/TB)    // 50
#define CTVM (C_*T_*V_*M_)   // 960000
#define TVM  (T_*V_*M_)      // 15000
#define VM   (V_*M_)         // 50
#define XPITCH 72         // shorts; 144B rows

typedef short  short8  __attribute__((ext_vector_type(8)));
typedef float  float4_ __attribute__((ext_vector_type(4)));
typedef unsigned short ushort4_ __attribute__((ext_vector_type(4)));

__device__ __forceinline__ short f2bf(float f) {   // fp32 -> bf16 RNE (prep)
    uint32_t u = __float_as_uint(f);
    u += 0x7FFFu + ((u >> 16) & 1u);
    return (short)(u >> 16);
}
// packed RNE: lo=bf16(a), hi=bf16(b). Proven bit-exact in round 5.
__device__ __forceinline__ unsigned pk2bf(float a, float b) {
    unsigned ua = __float_as_uint(a), ub = __float_as_uint(b);
    ua += 0x7FFFu + ((ua >> 16) & 1u);
    ub += 0x7FFFu + ((ub >> 16) & 1u);
    return __builtin_amdgcn_perm(ub, ua, 0x07060302u);
}
__device__ __forceinline__ float bf2f(unsigned short u) {
    return __uint_as_float(((unsigned)u) << 16);
}

// prep: W -> bf16 [os][c]; PA -> bf16 transposed+padded [s][w32][v32]; BN fold.
__global__ void stgcn_prep(const float* __restrict__ Wc, const float* __restrict__ PA,
                           const float* __restrict__ g,  const float* __restrict__ b,
                           const float* __restrict__ mn, const float* __restrict__ vr,
                           short* __restrict__ Wb, short* __restrict__ PAb,
                           float* __restrict__ scl, float* __restrict__ sft)
{
    const int i = blockIdx.x * 256 + threadIdx.x;
    if (i < OS_ * C_) Wb[i] = f2bf(Wc[i]);
    const int r = i - OS_ * C_;
    if (r >= 0 && r < S_ * 32 * 32) {
        const int s = r >> 10, rem = r & 1023, wp = rem >> 5, vp = rem & 31;
        const float val = (wp < V_ && vp < V_) ? PA[s * V_ * V_ + vp * V_ + wp] : 0.0f;
        PAb[r] = f2bf(val);
    }
    const int q = r - S_ * 32 * 32;
    if (q >= 0 && q < O_) {
        const float sc = g[q] * rsqrtf(vr[q] + 1e-5f);
        scl[q] = sc;
        sft[q] = b[q] - mn[q] * sc;
    }
}

__global__ __launch_bounds__(256, 3)
void stgcn_main(const float* __restrict__ x, const float* __restrict__ cb,
                const short* __restrict__ Wb, const short* __restrict__ PAb,
                const float* __restrict__ sclg, const float* __restrict__ sftg,
                float* __restrict__ out)
{
    __shared__ short Xb[2][64 * XPITCH];   // 18.4 KB (double-buffered)
    __shared__ uint2 scr[4 * 12 * 64];     // 24.6 KB wave-private handoff
    __shared__ float sclS[O_], sftS[O_];   // total 43,520 B

    const int tid  = threadIdx.x;
    const int wv   = tid >> 6;
    const int lane = tid & 63;
    const int quad = lane >> 4;
    const int l15  = lane & 15;

    const int n  = blockIdx.x / NT_BLK;
    const int t0 = (blockIdx.x % NT_BLK) * TB;
    const size_t xbase = (size_t)n * CTVM;

    // zero v-pad rows (pos 25..31, 57..63) of BOTH X buffers, once
    for (int i = tid; i < 2 * 14 * XPITCH; i += 256) {
        const int bf = i / (14 * XPITCH);
        const int r  = i - bf * (14 * XPITCH);
        const int pr = r / XPITCH, cc = r - pr * XPITCH;
        const int pos = (pr < 7) ? (25 + pr) : (50 + pr);
        Xb[bf][pos * XPITCH + cc] = 0;
    }
    if (tid < O_) { sclS[tid] = sclg[tid]; sftS[tid] = sftg[tid]; }

    // ---- wave-constant fragments ----
    const int osb = wv * 16;              // wave's o-block
    short8 aW[3][2];                      // stage-1 B: B[k=c][n=os]
    #pragma unroll
    for (int s = 0; s < 3; ++s)
        #pragma unroll
        for (int ks = 0; ks < 2; ++ks)
            aW[s][ks] = *(const short8*)(Wb + (s * 64 + osb + l15) * C_ + ks * 32 + quad * 8);

    float cbw[3];                         // stage-1 bias per COLUMN (os = l15)
    #pragma unroll
    for (int s = 0; s < 3; ++s) cbw[s] = cb[s * 64 + osb + l15];

    short8 bPf[3][2];                     // stage-2 B: B[k=v][n=w], both w-halves
    #pragma unroll
    for (int s = 0; s < 3; ++s)
        #pragma unroll
        for (int wh = 0; wh < 2; ++wh)
            bPf[s][wh] = *(const short8*)(PAb + s * 1024 + (wh * 16 + l15) * 32 + quad * 8);

    // ---- prologue: stage t0 into Xb[0] (R0-proven code) ----
    {
        const float* xt = x + xbase + (size_t)t0 * VM;
        #pragma unroll
        for (int k = 0; k < 4; ++k) {
            const int p = tid + k * 256;           // 800 (cpair, v) pairs
            if (p < 800) {
                const int v = p % 25, cp = p / 25;
                const float2 f0 = *(const float2*)(xt + (size_t)(2 * cp)     * TVM + v * 2);
                const float2 f1 = *(const float2*)(xt + (size_t)(2 * cp + 1) * TVM + v * 2);
                ((unsigned*)Xb[0])[v * 36 + cp]        = pk2bf(f0.x, f1.x);  // m=0
                ((unsigned*)Xb[0])[(32 + v) * 36 + cp] = pk2bf(f0.y, f1.y);  // m=1
            }
        }
    }

    int cur = 0;
    for (int tt = 0; tt < TB; ++tt) {
        __syncthreads();   // B0 (the ONLY barrier): Xb[cur] staged

        // ---- issue prefetch loads for t+1 (consumed at iteration end) ----
        float2 R0[4], R1[4];
        const bool pf = (tt + 1 < TB);
        if (pf) {
            const float* xt = x + xbase + (size_t)(t0 + tt + 1) * VM;
            #pragma unroll
            for (int k = 0; k < 4; ++k) {
                const int p = tid + k * 256;
                if (p < 800) {
                    const int v = p % 25, cp = p / 25;
                    R0[k] = *(const float2*)(xt + (size_t)(2 * cp)     * TVM + v * 2);
                    R1[k] = *(const float2*)(xt + (size_t)(2 * cp + 1) * TVM + v * 2);
                }
            }
        }

        // ---- stage-1 A frags + residual from Xb[cur] ----
        const short* Xc = Xb[cur];
        short8 bX[4][2];                  // A[m=pos][k=c]
        #pragma unroll
        for (int nt = 0; nt < 4; ++nt)
            #pragma unroll
            for (int ks = 0; ks < 2; ++ks)
                bX[nt][ks] = *(const short8*)(Xc + (nt * 16 + l15) * XPITCH + ks * 32 + quad * 8);

        ushort4_ res[2][2];               // [m][wh]: residual bf16, o = osb+4*quad+r
        #pragma unroll
        for (int m = 0; m < 2; ++m)
            #pragma unroll
            for (int wh = 0; wh < 2; ++wh)
                res[m][wh] = *(const ushort4_*)(Xc + (m * 32 + wh * 16 + l15) * XPITCH + osb + quad * 4);

        // ---- stage 1: D[pos][o] = X^T·W^T + cb; pack -> wave-private scratch ----
        #pragma unroll
        for (int s = 0; s < 3; ++s) {
            #pragma unroll
            for (int nt = 0; nt < 4; ++nt) {
                float4_ acc = { cbw[s], cbw[s], cbw[s], cbw[s] };
                acc = __builtin_amdgcn_mfma_f32_16x16x32_bf16(bX[nt][0], aW[s][0], acc, 0, 0, 0);
                acc = __builtin_amdgcn_mfma_f32_16x16x32_bf16(bX[nt][1], aW[s][1], acc, 0, 0, 0);
                scr[wv * 768 + (s * 4 + nt) * 64 + lane] =
                    make_uint2(pk2bf(acc[0], acc[1]), pk2bf(acc[2], acc[3]));
            }
        }

        // same-wave RAW ordering for scratch (no barrier: scr[wv] is private)
        asm volatile("s_waitcnt lgkmcnt(0)" ::: "memory");

        // ---- stage 2: z[m][wh] = sum_s Y_s[o][v]·PA_s[v][w] ----
        float4_ z[2][2];
        #pragma unroll
        for (int m = 0; m < 2; ++m)
            #pragma unroll
            for (int wh = 0; wh < 2; ++wh) { z[m][wh][0]=0.f; z[m][wh][1]=0.f; z[m][wh][2]=0.f; z[m][wh][3]=0.f; }

        const int lanepart = (((lane >> 4) & 1) * 32) + l15;   // src-lane base
        const int ntq      = (lane >> 5);                      // quad>>1
        #pragma unroll
        for (int s = 0; s < 3; ++s) {
            #pragma unroll
            for (int m = 0; m < 2; ++m) {
                union { short8 s8; uint2 u2[2]; } aY;
                const int base = wv * 768 + (s * 4 + 2 * m + ntq) * 64;
                aY.u2[0] = scr[base + lanepart];
                aY.u2[1] = scr[base + lanepart + 16];
                #pragma unroll
                for (int wh = 0; wh < 2; ++wh)
                    z[m][wh] = __builtin_amdgcn_mfma_f32_16x16x32_bf16(aY.s8, bPf[s][wh], z[m][wh], 0, 0, 0);
            }
        }

        // ---- epilogue: BN + relu + residual + relu; dense float2 stores ----
        const int t = t0 + tt;
        #pragma unroll
        for (int wh = 0; wh < 2; ++wh) {
            const int w = wh * 16 + l15;
            if (w < V_) {
                #pragma unroll
                for (int r = 0; r < 4; ++r) {
                    const int o = osb + quad * 4 + r;
                    const float sc = sclS[o], sh = sftS[o];
                    float q0 = fmaf(z[0][wh][r], sc, sh);
                    q0 = fmaxf(q0, 0.0f);
                    q0 = fmaxf(q0 + bf2f((unsigned short)res[0][wh][r]), 0.0f);
                    float q1 = fmaf(z[1][wh][r], sc, sh);
                    q1 = fmaxf(q1, 0.0f);
                    q1 = fmaxf(q1 + bf2f((unsigned short)res[1][wh][r]), 0.0f);
                    *(float2*)(out + xbase + (size_t)o * TVM + (size_t)t * VM + w * 2) =
                        make_float2(q0, q1);
                }
            }
        }

        // ---- convert prefetched regs into the other X buffer (R0 code) ----
        if (pf) {
            short* Xn = Xb[cur ^ 1];
            #pragma unroll
            for (int k = 0; k < 4; ++k) {
                const int p = tid + k * 256;
                if (p < 800) {
                    const int v = p % 25, cp = p / 25;
                    ((unsigned*)Xn)[v * 36 + cp]        = pk2bf(R0[k].x, R1[k].x);
                    ((unsigned*)Xn)[(32 + v) * 36 + cp] = pk2bf(R0[k].y, R1[k].y);
                }
            }
        }
        cur ^= 1;
    }
}

extern "C" void kernel_launch(void* const* d_in, const int* in_sizes, int n_in,
                              void* d_out, int out_size, void* d_ws, size_t ws_size,
                              hipStream_t stream)
{
    const float* x    = (const float*)d_in[0];  // (32,64,300,25,2)
    const float* PA   = (const float*)d_in[1];  // (3,25,25)
    const float* Wc   = (const float*)d_in[2];  // (192,64)
    const float* cb   = (const float*)d_in[3];  // (192,)
    const float* bn_g = (const float*)d_in[4];
    const float* bn_b = (const float*)d_in[5];
    const float* bn_m = (const float*)d_in[6];
    const float* bn_v = (const float*)d_in[7];
    float* out = (float*)d_out;

    char* ws = (char*)d_ws;
    short* Wb  = (short*)ws;                    // 12288 bf16
    short* PAb = (short*)(ws + 24576);          //  3072 bf16
    float* scl = (float*)(ws + 30720);          //    64 f32
    float* sft = (float*)(ws + 30976);          //    64 f32

    stgcn_prep<<<61, 256, 0, stream>>>(Wc, PA, bn_g, bn_b, bn_m, bn_v, Wb, PAb, scl, sft);
    stgcn_main<<<N_ * NT_BLK, 256, 0, stream>>>(x, cb, Wb, PAb, scl, sft, out);
}

// Round 7
// 275.003 us; speedup vs baseline: 1.4679x; 1.0107x over previous
//
#include <hip/hip_runtime.h>
#include <cstddef>
#include <cstdint>

// ST-GCN block. Round-7: pin prefetch issue with asm loads; store-drain-free barrier.
//  Keeps R6's validated structure: single barrier/iter, wave-private stage1->stage2
//  scratch handoff (conflicts 6.6M->2.3M), o-block wave mapping, dense f2 stores.
//  New in R7 (diagnosis: VGPR=84 proves compiler SINKS the prefetch loads to the
//  convert site -> full load latency exposed every iteration; ~25% mem duty cycle):
//   - Prefetch loads are inline-asm global_load_dwordx2 (volatile+memory clobber),
//     issued immediately after B0 -> cannot be sunk. Results waited via a
//     DATA-CARRYING fence (s_waitcnt vmcnt(0) with "+v" on all 8 float2s) right
//     before the convert -> issue-early / wait-late, compiler-proof (rule #18:
//     sched_barrier(0) after the fence).
//   - B0 = {s_waitcnt lgkmcnt(0); s_barrier} (NOT __syncthreads, which drains
//     vmcnt(0)): epilogue stores never block an iteration. Convert moved BEFORE
//     the epilogue so the fence's vmcnt(0) sees only long-landed ops.
// Sync proof: [B0_t, B0_{t+1}): Xb[cur] read-only (bX+res, before any Xb write),
//   Xb[cur^1] written only by convert; B0's lgkmcnt(0)+barrier orders convert
//   writes before next iter's reads. scr[wv] wave-private (lgkmcnt-ordered).
#define N_  32
#define C_  64
#define T_  300
#define V_  25
#define M_  2
#define S_  3
#define O_  64
#define OS_ 192
#define TB  6             // t-values per block
#define NT_BLK (T_/TB)    // 50
#define CTVM (C_*T_*V_*M_)   // 960000
#define TVM  (T_*V_*M_)      // 15000
#define VM   (V_*M_)         // 50
#define XPITCH 72         // shorts; 144B rows

typedef short  short8  __attribute__((ext_vector_type(8)));
typedef float  float4_ __attribute__((ext_vector_type(4)));
typedef float  f2v     __attribute__((ext_vector_type(2)));
typedef unsigned short ushort4_ __attribute__((ext_vector_type(4)));

__device__ __forceinline__ short f2bf(float f) {   // fp32 -> bf16 RNE (prep)
    uint32_t u = __float_as_uint(f);
    u += 0x7FFFu + ((u >> 16) & 1u);
    return (short)(u >> 16);
}
// packed RNE: lo=bf16(a), hi=bf16(b). Proven bit-exact (R5/R6).
__device__ __forceinline__ unsigned pk2bf(float a, float b) {
    unsigned ua = __float_as_uint(a), ub = __float_as_uint(b);
    ua += 0x7FFFu + ((ua >> 16) & 1u);
    ub += 0x7FFFu + ((ub >> 16) & 1u);
    return __builtin_amdgcn_perm(ub, ua, 0x07060302u);
}
__device__ __forceinline__ float bf2f(unsigned short u) {
    return __uint_as_float(((unsigned)u) << 16);
}
// pinned-issue 8B load: volatile asm cannot be sunk by the scheduler.
__device__ __forceinline__ f2v gload2(const float* p) {
    f2v r;
    asm volatile("global_load_dwordx2 %0, %1, off" : "=v"(r) : "v"(p) : "memory");
    return r;
}
// barrier with LDS-only drain (stores stay in flight across iterations)
#define SYNC_LGKM() do { \
    asm volatile("s_waitcnt lgkmcnt(0)" ::: "memory"); \
    __builtin_amdgcn_s_barrier(); \
    asm volatile("" ::: "memory"); } while (0)

// prep: W -> bf16 [os][c]; PA -> bf16 transposed+padded [s][w32][v32]; BN fold.
__global__ void stgcn_prep(const float* __restrict__ Wc, const float* __restrict__ PA,
                           const float* __restrict__ g,  const float* __restrict__ b,
                           const float* __restrict__ mn, const float* __restrict__ vr,
                           short* __restrict__ Wb, short* __restrict__ PAb,
                           float* __restrict__ scl, float* __restrict__ sft)
{
    const int i = blockIdx.x * 256 + threadIdx.x;
    if (i < OS_ * C_) Wb[i] = f2bf(Wc[i]);
    const int r = i - OS_ * C_;
    if (r >= 0 && r < S_ * 32 * 32) {
        const int s = r >> 10, rem = r & 1023, wp = rem >> 5, vp = rem & 31;
        const float val = (wp < V_ && vp < V_) ? PA[s * V_ * V_ + vp * V_ + wp] : 0.0f;
        PAb[r] = f2bf(val);
    }
    const int q = r - S_ * 32 * 32;
    if (q >= 0 && q < O_) {
        const float sc = g[q] * rsqrtf(vr[q] + 1e-5f);
        scl[q] = sc;
        sft[q] = b[q] - mn[q] * sc;
    }
}

__global__ __launch_bounds__(256, 3)
void stgcn_main(const float* __restrict__ x, const float* __restrict__ cb,
                const short* __restrict__ Wb, const short* __restrict__ PAb,
                const float* __restrict__ sclg, const float* __restrict__ sftg,
                float* __restrict__ out)
{
    __shared__ short Xb[2][64 * XPITCH];   // 18.4 KB (double-buffered)
    __shared__ uint2 scr[4 * 12 * 64];     // 24.6 KB wave-private handoff
    __shared__ float sclS[O_], sftS[O_];   // total 43,520 B -> 3 blocks/CU

    const int tid  = threadIdx.x;
    const int wv   = tid >> 6;
    const int lane = tid & 63;
    const int quad = lane >> 4;
    const int l15  = lane & 15;

    const int n  = blockIdx.x / NT_BLK;
    const int t0 = (blockIdx.x % NT_BLK) * TB;
    const size_t xbase = (size_t)n * CTVM;

    // zero v-pad rows (pos 25..31, 57..63) of BOTH X buffers, once
    for (int i = tid; i < 2 * 14 * XPITCH; i += 256) {
        const int bf = i / (14 * XPITCH);
        const int r  = i - bf * (14 * XPITCH);
        const int pr = r / XPITCH, cc = r - pr * XPITCH;
        const int pos = (pr < 7) ? (25 + pr) : (50 + pr);
        Xb[bf][pos * XPITCH + cc] = 0;
    }
    if (tid < O_) { sclS[tid] = sclg[tid]; sftS[tid] = sftg[tid]; }

    // ---- wave-constant fragments ----
    const int osb = wv * 16;              // wave's o-block
    short8 aW[3][2];                      // stage-1 B: B[k=c][n=os]
    #pragma unroll
    for (int s = 0; s < 3; ++s)
        #pragma unroll
        for (int ks = 0; ks < 2; ++ks)
            aW[s][ks] = *(const short8*)(Wb + (s * 64 + osb + l15) * C_ + ks * 32 + quad * 8);

    float cbw[3];                         // stage-1 bias per COLUMN (os = l15)
    #pragma unroll
    for (int s = 0; s < 3; ++s) cbw[s] = cb[s * 64 + osb + l15];

    short8 bPf[3][2];                     // stage-2 B: B[k=v][n=w], both w-halves
    #pragma unroll
    for (int s = 0; s < 3; ++s)
        #pragma unroll
        for (int wh = 0; wh < 2; ++wh)
            bPf[s][wh] = *(const short8*)(PAb + s * 1024 + (wh * 16 + l15) * 32 + quad * 8);

    // per-thread prefetch geometry (k=0..2 always valid; k=3 clamped to p=799)
    int cpk[4], vk[4];
    #pragma unroll
    for (int k = 0; k < 4; ++k) {
        int p = tid + k * 256; if (p > 799) p = 799;
        cpk[k] = p / 25; vk[k] = p - cpk[k] * 25;
    }

    // ---- prologue: stage t0 into Xb[0] (blocking, once per block) ----
    {
        const float* xt = x + xbase + (size_t)t0 * VM;
        #pragma unroll
        for (int k = 0; k < 4; ++k) {
            const int p = tid + k * 256;
            if (p < 800) {
                const int v = vk[k], cp = cpk[k];
                const float2 f0 = *(const float2*)(xt + (size_t)(2 * cp)     * TVM + v * 2);
                const float2 f1 = *(const float2*)(xt + (size_t)(2 * cp + 1) * TVM + v * 2);
                ((unsigned*)Xb[0])[v * 36 + cp]        = pk2bf(f0.x, f1.x);  // m=0
                ((unsigned*)Xb[0])[(32 + v) * 36 + cp] = pk2bf(f0.y, f1.y);  // m=1
            }
        }
    }

    int cur = 0;
    for (int tt = 0; tt < TB; ++tt) {
        SYNC_LGKM();   // B0 (only barrier): Xb[cur] staged; stores NOT drained

        // ---- pinned-issue prefetch for t+1 (waited at convert, below) ----
        f2v R0[4], R1[4];
        const bool pf = (tt + 1 < TB);
        if (pf) {
            const float* xt = x + xbase + (size_t)(t0 + tt + 1) * VM;
            #pragma unroll
            for (int k = 0; k < 4; ++k) {
                const float* g0 = xt + (size_t)(2 * cpk[k]) * TVM + vk[k] * 2;
                R0[k] = gload2(g0);
                R1[k] = gload2(g0 + TVM);
            }
        }

        // ---- stage-1 A frags + residual from Xb[cur] ----
        const short* Xc = Xb[cur];
        short8 bX[4][2];                  // A[m=pos][k=c]
        #pragma unroll
        for (int nt = 0; nt < 4; ++nt)
            #pragma unroll
            for (int ks = 0; ks < 2; ++ks)
                bX[nt][ks] = *(const short8*)(Xc + (nt * 16 + l15) * XPITCH + ks * 32 + quad * 8);

        ushort4_ res[2][2];               // [m][wh]: residual bf16, o = osb+4*quad+r
        #pragma unroll
        for (int m = 0; m < 2; ++m)
            #pragma unroll
            for (int wh = 0; wh < 2; ++wh)
                res[m][wh] = *(const ushort4_*)(Xc + (m * 32 + wh * 16 + l15) * XPITCH + osb + quad * 4);

        // ---- stage 1: D[pos][o] = X^T·W^T + cb; pack -> wave-private scratch ----
        #pragma unroll
        for (int s = 0; s < 3; ++s) {
            #pragma unroll
            for (int nt = 0; nt < 4; ++nt) {
                float4_ acc = { cbw[s], cbw[s], cbw[s], cbw[s] };
                acc = __builtin_amdgcn_mfma_f32_16x16x32_bf16(bX[nt][0], aW[s][0], acc, 0, 0, 0);
                acc = __builtin_amdgcn_mfma_f32_16x16x32_bf16(bX[nt][1], aW[s][1], acc, 0, 0, 0);
                scr[wv * 768 + (s * 4 + nt) * 64 + lane] =
                    make_uint2(pk2bf(acc[0], acc[1]), pk2bf(acc[2], acc[3]));
            }
        }

        // same-wave RAW ordering for scratch (scr[wv] is private; no barrier)
        asm volatile("s_waitcnt lgkmcnt(0)" ::: "memory");
        __builtin_amdgcn_sched_barrier(0);

        // ---- stage 2: z[m][wh] = sum_s Y_s[o][v]·PA_s[v][w] ----
        float4_ z[2][2];
        #pragma unroll
        for (int m = 0; m < 2; ++m)
            #pragma unroll
            for (int wh = 0; wh < 2; ++wh) { z[m][wh][0]=0.f; z[m][wh][1]=0.f; z[m][wh][2]=0.f; z[m][wh][3]=0.f; }

        const int lanepart = (((lane >> 4) & 1) * 32) + l15;   // src-lane base
        const int ntq      = (lane >> 5);                      // quad>>1
        #pragma unroll
        for (int s = 0; s < 3; ++s) {
            #pragma unroll
            for (int m = 0; m < 2; ++m) {
                union { short8 s8; uint2 u2[2]; } aY;
                const int base = wv * 768 + (s * 4 + 2 * m + ntq) * 64;
                aY.u2[0] = scr[base + lanepart];
                aY.u2[1] = scr[base + lanepart + 16];
                #pragma unroll
                for (int wh = 0; wh < 2; ++wh)
                    z[m][wh] = __builtin_amdgcn_mfma_f32_16x16x32_bf16(aY.s8, bPf[s][wh], z[m][wh], 0, 0, 0);
            }
        }

        // ---- convert prefetched regs into Xb[cur^1] (BEFORE epilogue stores) ----
        if (pf) {
            // data-carrying fence: every use below consumes these fenced defs
            asm volatile("s_waitcnt vmcnt(0)"
                : "+v"(R0[0]), "+v"(R0[1]), "+v"(R0[2]), "+v"(R0[3]),
                  "+v"(R1[0]), "+v"(R1[1]), "+v"(R1[2]), "+v"(R1[3])
                :: "memory");
            __builtin_amdgcn_sched_barrier(0);
            short* Xn = Xb[cur ^ 1];
            #pragma unroll
            for (int k = 0; k < 4; ++k) {
                const int p = tid + k * 256;
                if (p < 800) {
                    const int v = vk[k], cp = cpk[k];
                    ((unsigned*)Xn)[v * 36 + cp]        = pk2bf(R0[k][0], R1[k][0]);  // m=0
                    ((unsigned*)Xn)[(32 + v) * 36 + cp] = pk2bf(R0[k][1], R1[k][1]);  // m=1
                }
            }
        }

        // ---- epilogue: BN + relu + residual + relu; dense float2 stores ----
        const int t = t0 + tt;
        #pragma unroll
        for (int wh = 0; wh < 2; ++wh) {
            const int w = wh * 16 + l15;
            if (w < V_) {
                #pragma unroll
                for (int r = 0; r < 4; ++r) {
                    const int o = osb + quad * 4 + r;
                    const float sc = sclS[o], sh = sftS[o];
                    float q0 = fmaf(z[0][wh][r], sc, sh);
                    q0 = fmaxf(q0, 0.0f);
                    q0 = fmaxf(q0 + bf2f((unsigned short)res[0][wh][r]), 0.0f);
                    float q1 = fmaf(z[1][wh][r], sc, sh);
                    q1 = fmaxf(q1, 0.0f);
                    q1 = fmaxf(q1 + bf2f((unsigned short)res[1][wh][r]), 0.0f);
                    *(float2*)(out + xbase + (size_t)o * TVM + (size_t)t * VM + w * 2) =
                        make_float2(q0, q1);
                }
            }
        }
        cur ^= 1;
    }
}

extern "C" void kernel_launch(void* const* d_in, const int* in_sizes, int n_in,
                              void* d_out, int out_size, void* d_ws, size_t ws_size,
                              hipStream_t stream)
{
    const float* x    = (const float*)d_in[0];  // (32,64,300,25,2)
    const float* PA   = (const float*)d_in[1];  // (3,25,25)
    const float* Wc   = (const float*)d_in[2];  // (192,64)
    const float* cb   = (const float*)d_in[3];  // (192,)
    const float* bn_g = (const float*)d_in[4];
    const float* bn_b = (const float*)d_in[5];
    const float* bn_m = (const float*)d_in[6];
    const float* bn_v = (const float*)d_in[7];
    float* out = (float*)d_out;

    char* ws = (char*)d_ws;
    short* Wb  = (short*)ws;                    // 12288 bf16
    short* PAb = (short*)(ws + 24576);          //  3072 bf16
    float* scl = (float*)(ws + 30720);          //    64 f32
    float* sft = (float*)(ws + 30976);          //    64 f32

    stgcn_prep<<<61, 256, 0, stream>>>(Wc, PA, bn_g, bn_b, bn_m, bn_v, Wb, PAb, scl, sft);
    stgcn_main<<<N_ * NT_BLK, 256, 0, stream>>>(x, cb, Wb, PAb, scl, sft, out);
}